// Round 4
// baseline (21.028 us; speedup 1.0000x reference)
//
#include <hip/hip_runtime.h>
#include <hip/hip_bf16.h>

#define D_Z 64
#define D_TOTAL 16448
#define NY 16384
#define N_ZB 8
#define N_YB (NY / 16)   // 1024

typedef __attribute__((ext_vector_type(8))) short bf16x8;
typedef __attribute__((ext_vector_type(4))) float f32x4;

__device__ __forceinline__ short f2bf(float x) {
    union { __hip_bfloat16 h; short s; } u;
    u.h = __float2bfloat16(x);   // RNE; compiler pairs into v_cvt_pk_bf16_f32
    return u.s;
}

__device__ __forceinline__ bf16x8 packbf(float4 a, float4 b) {
    bf16x8 r = { f2bf(a.x), f2bf(a.y), f2bf(a.z), f2bf(a.w),
                 f2bf(b.x), f2bf(b.y), f2bf(b.z), f2bf(b.w) };
    return r;
}

// Grid: blocks 0..7 -> z-part (cols 0..63, one 16-sample chunk each).
//       blocks 8..1031 -> y-part: 16 y-cols x 128 samples, pure MFMA
//       (z-dot K=64 as 2 MFMAs + block-diag triangular corr as 1 MFMA).
__global__ __launch_bounds__(256) void sv_kernel(
    const float* __restrict__ m,
    const float* __restrict__ Lz,     // tril(64), row-major tril order
    const float* __restrict__ Ly,     // N * 36, per-block tril(8)
    const float* __restrict__ Lyz,    // [NY x 64] row-major
    const float* __restrict__ eps,    // [128, 16448]
    float* __restrict__ out)          // [128, 16448]
{
    __shared__ float eps_z[16][D_Z];  // z-part staging only (4 KB)

    const int tid = threadIdx.x;
    const int bb  = blockIdx.x;

    if (bb >= N_ZB) {
        // ================= y-part =================
        const int t    = bb - N_ZB;
        const int j0   = t << 4;           // base y-col of this 16-col tile
        const int w    = tid >> 6;         // wave 0..3 -> samples w*32..w*32+31
        const int lane = tid & 63;
        const int ln15 = lane & 15;
        const int lg   = lane >> 4;        // 0..3

        const int jy = j0 + ln15;          // y-col (0..16383)
        const int jg = D_Z + jy;           // global out col

        // ---- B z-fragments: Lyz row jy (K=64 as 2 chunks of 32) ----
        const float* lyzrow = Lyz + (size_t)jy * D_Z + lg * 8;
        const bf16x8 bz0 = packbf(*reinterpret_cast<const float4*>(lyzrow),
                                  *reinterpret_cast<const float4*>(lyzrow + 4));
        const bf16x8 bz1 = packbf(*reinterpret_cast<const float4*>(lyzrow + 32),
                                  *reinterpret_cast<const float4*>(lyzrow + 36));

        // ---- B y-fragment: block-diagonal triangular Ly ----
        // B[k=lg*8+e][col=ln15] nonzero iff lg == ln15>>3, value = padded Ly row.
        const int r = ln15 & 7;
        const float* lyp = Ly + (size_t)(jy >> 3) * 36 + r * (r + 1) / 2;
        float lyr[8];
        #pragma unroll
        for (int c = 0; c < 8; ++c) lyr[c] = (c <= r) ? lyp[c] : 0.0f;
        bf16x8 by = {0, 0, 0, 0, 0, 0, 0, 0};
        if (lg == (ln15 >> 3)) {
            by = packbf(make_float4(lyr[0], lyr[1], lyr[2], lyr[3]),
                        make_float4(lyr[4], lyr[5], lyr[6], lyr[7]));
        }

        const float mj = m[jg];

        #pragma unroll
        for (int mt = 0; mt < 2; ++mt) {
            const int srow = (w << 5) + (mt << 4) + ln15;   // A row = sample
            const float* er = eps + (size_t)srow * D_TOTAL;

            // A z-fragments (eps_z slice, K=64)
            const bf16x8 az0 = packbf(*reinterpret_cast<const float4*>(er + lg * 8),
                                      *reinterpret_cast<const float4*>(er + lg * 8 + 4));
            const bf16x8 az1 = packbf(*reinterpret_cast<const float4*>(er + 32 + lg * 8),
                                      *reinterpret_cast<const float4*>(er + 32 + lg * 8 + 4));
            // A y-fragment: k<16 -> eps_y[s, j0+k]; k>=16 don't-care (B=0 there)
            const float* ey = er + D_Z + j0 + ((lg & 1) << 3);
            const bf16x8 ay = packbf(*reinterpret_cast<const float4*>(ey),
                                     *reinterpret_cast<const float4*>(ey + 4));

            f32x4 acc = {0.f, 0.f, 0.f, 0.f};
            acc = __builtin_amdgcn_mfma_f32_16x16x32_bf16(az0, bz0, acc, 0, 0, 0);
            acc = __builtin_amdgcn_mfma_f32_16x16x32_bf16(az1, bz1, acc, 0, 0, 0);
            acc = __builtin_amdgcn_mfma_f32_16x16x32_bf16(ay,  by,  acc, 0, 0, 0);

            const int sbase = (w << 5) + (mt << 4) + (lg << 2);  // D row = lg*4+reg
            #pragma unroll
            for (int reg = 0; reg < 4; ++reg) {
                out[(size_t)(sbase + reg) * D_TOTAL + jg] = acc[reg] + mj;
            }
        }
    } else {
        // ========== z-part: cols 0..63, sample chunk bb (proven) ==========
        const int s0 = bb * 16;
        {
            const int row = tid >> 4;
            const int c4  = (tid & 15) << 2;
            *reinterpret_cast<float4*>(&eps_z[row][c4]) =
                *reinterpret_cast<const float4*>(&eps[(size_t)(s0 + row) * D_TOTAL + c4]);
        }
        __syncthreads();

        const int j  = tid & 63;
        const int sg = tid >> 6;
        const float mj = m[j];
        const float* lzr = Lz + j * (j + 1) / 2;

        #pragma unroll
        for (int ss = 0; ss < 4; ++ss) {
            const int si = (sg << 2) + ss;
            float acc = mj;
            for (int k = 0; k <= j; ++k) acc += eps_z[si][k] * lzr[k];
            out[(size_t)(s0 + si) * D_TOTAL + j] = acc;
        }
    }
}

extern "C" void kernel_launch(void* const* d_in, const int* in_sizes, int n_in,
                              void* d_out, int out_size, void* d_ws, size_t ws_size,
                              hipStream_t stream) {
    const float* m   = (const float*)d_in[0];
    const float* Lz  = (const float*)d_in[1];
    const float* Ly  = (const float*)d_in[2];
    const float* Lyz = (const float*)d_in[3];
    const float* eps = (const float*)d_in[4];
    float* out = (float*)d_out;

    dim3 grid(N_ZB + N_YB);  // 1032
    dim3 block(256);
    hipLaunchKernelGGL(sv_kernel, grid, block, 0, stream,
                       m, Lz, Ly, Lyz, eps, out);
}

// Round 5
// 14.374 us; speedup vs baseline: 1.4629x; 1.4629x over previous
//
#include <hip/hip_runtime.h>
#include <hip/hip_bf16.h>

#define D_Z 64
#define D_TOTAL 16448
#define NY 16384
#define TJ 32
#define N_YB (NY / TJ)   // 512
#define N_ZB 8

typedef __attribute__((ext_vector_type(8))) short bf16x8;
typedef __attribute__((ext_vector_type(4))) float f32x4;

__device__ __forceinline__ short f2bf(float x) {
    union { __hip_bfloat16 h; short s; } u;
    u.h = __float2bfloat16(x);   // RNE; pairs into v_cvt_pk_bf16_f32
    return u.s;
}

__device__ __forceinline__ bf16x8 packbf(float4 a, float4 b) {
    bf16x8 r = { f2bf(a.x), f2bf(a.y), f2bf(a.z), f2bf(a.w),
                 f2bf(b.x), f2bf(b.y), f2bf(b.z), f2bf(b.w) };
    return r;
}

// Grid: blocks 0..7 -> z-part (cols 0..63, one 16-sample chunk each).
//       blocks 8..519 -> y-part: 32 y-cols x 128 samples.
//       Staged: eps_z/eps_y/Lyz -> LDS (bf16, XOR-swizzled), frag reads b128.
__global__ __launch_bounds__(256) void sv_kernel(
    const float* __restrict__ m,
    const float* __restrict__ Lz,     // tril(64), row-major tril order
    const float* __restrict__ Ly,     // N * 36, per-block tril(8)
    const float* __restrict__ Lyz,    // [NY x 64] row-major
    const float* __restrict__ eps,    // [128, 16448]
    float* __restrict__ out)          // [128, 16448]
{
    __shared__ __align__(16) short zs[128 * 64];  // eps_z bf16 swz  (16 KB)
    __shared__ __align__(16) short ys[128 * 32];  // eps_y tile bf16 ( 8 KB)
    __shared__ __align__(16) short ls[32 * 64];   // Lyz tile bf16   ( 4 KB)

    const int tid = threadIdx.x;
    const int bb  = blockIdx.x;

    if (bb >= N_ZB) {
        // ================= y-part =================
        const int j0 = (bb - N_ZB) * TJ;
        char* zsb = (char*)zs;
        char* ysb = (char*)ys;
        char* lsb = (char*)ls;

        // ---- stage eps_z [128 rows][64 cols] fp32 -> bf16, swizzled ----
        {
            const int r0 = tid >> 3;          // 0..31
            const int c8 = (tid & 7) << 3;    // 0..56
            #pragma unroll
            for (int it = 0; it < 4; ++it) {
                const int row = r0 + (it << 5);
                const float* p = eps + (size_t)row * D_TOTAL + c8;
                const bf16x8 v = packbf(*(const float4*)p, *(const float4*)(p + 4));
                *(bf16x8*)(zsb + row * 128 + ((c8 << 1) ^ ((row & 7) << 4))) = v;
            }
            // ---- stage Lyz panel [32 rows][64 cols] ----
            const float* q = Lyz + (size_t)(j0 + r0) * D_Z + c8;
            const bf16x8 v = packbf(*(const float4*)q, *(const float4*)(q + 4));
            *(bf16x8*)(lsb + r0 * 128 + ((c8 << 1) ^ ((r0 & 7) << 4))) = v;
        }
        // ---- stage eps_y tile [128 rows][32 cols] ----
        {
            const int r0 = tid >> 2;          // 0..63
            const int c8 = (tid & 3) << 3;    // 0,8,16,24
            #pragma unroll
            for (int it = 0; it < 2; ++it) {
                const int row = r0 + (it << 6);
                const float* p = eps + (size_t)row * D_TOTAL + D_Z + j0 + c8;
                const bf16x8 v = packbf(*(const float4*)p, *(const float4*)(p + 4));
                *(bf16x8*)(ysb + row * 64 + ((c8 << 1) ^ ((row & 3) << 4))) = v;
            }
        }
        __syncthreads();

        const int w    = tid >> 6;
        const int lane = tid & 63;
        const int ln15 = lane & 15;
        const int lg   = lane >> 4;

        // ---- A-z fragments (held in regs, reused across both subtiles) ----
        bf16x8 az[2][2];
        #pragma unroll
        for (int mt = 0; mt < 2; ++mt) {
            const int row = (w << 5) + (mt << 4) + ln15;
            #pragma unroll
            for (int ks = 0; ks < 2; ++ks) {
                az[mt][ks] = *(const bf16x8*)(zsb + row * 128 +
                                (((ks << 6) + (lg << 4)) ^ ((row & 7) << 4)));
            }
        }

        #pragma unroll
        for (int st = 0; st < 2; ++st) {
            const int jy = j0 + (st << 4) + ln15;
            const int jg = D_Z + jy;

            // B-z fragments from LDS Lyz panel
            const int brow = (st << 4) + ln15;
            bf16x8 bz[2];
            #pragma unroll
            for (int ks = 0; ks < 2; ++ks) {
                bz[ks] = *(const bf16x8*)(lsb + brow * 128 +
                            (((ks << 6) + (lg << 4)) ^ ((brow & 7) << 4)));
            }

            // B-y fragment: block-diagonal triangular Ly (global, tiny)
            const int r = ln15 & 7;
            const float* lyp = Ly + (size_t)(jy >> 3) * 36 + r * (r + 1) / 2;
            bf16x8 by = {0, 0, 0, 0, 0, 0, 0, 0};
            if (lg == (ln15 >> 3)) {
                float lyr[8];
                #pragma unroll
                for (int c = 0; c < 8; ++c) lyr[c] = (c <= r) ? lyp[c] : 0.0f;
                by = packbf(make_float4(lyr[0], lyr[1], lyr[2], lyr[3]),
                            make_float4(lyr[4], lyr[5], lyr[6], lyr[7]));
            }

            const float mj = m[jg];

            #pragma unroll
            for (int mt = 0; mt < 2; ++mt) {
                const int srow = (w << 5) + (mt << 4) + ln15;
                const bf16x8 ay = *(const bf16x8*)(ysb + srow * 64 +
                        (((st << 5) + ((lg & 1) << 4)) ^ ((srow & 3) << 4)));

                f32x4 acc = {0.f, 0.f, 0.f, 0.f};
                acc = __builtin_amdgcn_mfma_f32_16x16x32_bf16(az[mt][0], bz[0], acc, 0, 0, 0);
                acc = __builtin_amdgcn_mfma_f32_16x16x32_bf16(az[mt][1], bz[1], acc, 0, 0, 0);
                acc = __builtin_amdgcn_mfma_f32_16x16x32_bf16(ay,        by,    acc, 0, 0, 0);

                const int sbase = (w << 5) + (mt << 4) + (lg << 2);
                #pragma unroll
                for (int reg = 0; reg < 4; ++reg) {
                    out[(size_t)(sbase + reg) * D_TOTAL + jg] = acc[reg] + mj;
                }
            }
        }
    } else {
        // ========== z-part: cols 0..63, sample chunk bb (proven) ==========
        float* ez = (float*)zs;   // reuse LDS as [16][64] fp32
        const int s0 = bb * 16;
        {
            const int row = tid >> 4;
            const int c4  = (tid & 15) << 2;
            *(float4*)(&ez[row * 64 + c4]) =
                *(const float4*)(&eps[(size_t)(s0 + row) * D_TOTAL + c4]);
        }
        __syncthreads();

        const int j  = tid & 63;
        const int sg = tid >> 6;
        const float mj = m[j];
        const float* lzr = Lz + j * (j + 1) / 2;

        #pragma unroll
        for (int ss = 0; ss < 4; ++ss) {
            const int si = (sg << 2) + ss;
            float acc = mj;
            for (int k = 0; k <= j; ++k) acc += ez[si * 64 + k] * lzr[k];
            out[(size_t)(s0 + si) * D_TOTAL + j] = acc;
        }
    }
}

extern "C" void kernel_launch(void* const* d_in, const int* in_sizes, int n_in,
                              void* d_out, int out_size, void* d_ws, size_t ws_size,
                              hipStream_t stream) {
    const float* m   = (const float*)d_in[0];
    const float* Lz  = (const float*)d_in[1];
    const float* Ly  = (const float*)d_in[2];
    const float* Lyz = (const float*)d_in[3];
    const float* eps = (const float*)d_in[4];
    float* out = (float*)d_out;

    dim3 grid(N_ZB + N_YB);  // 520
    dim3 block(256);
    hipLaunchKernelGGL(sv_kernel, grid, block, 0, stream,
                       m, Lz, Ly, Lyz, eps, out);
}